// Round 1
// baseline (161.833 us; speedup 1.0000x reference)
//
#include <hip/hip_runtime.h>
#include <hip/hip_bf16.h>

// MambaSP: 4-layer selective-scan SSM. B=32, L=4096, E=2, N=64, K=4, DT_RANK=1.
// Strategy: per layer, 3-phase chunked parallel scan (NC=32 chunks of CL=128):
//   K1: preprocess (conv+silu+softplus) + per-chunk (P=prod dA, S=local scan)
//   K2: tiny serial combine over chunks -> per-chunk initial states
//   K3: re-scan chunk with known init state, LDS-staged n-reduction, fused epilogue
// Bm/Cm are recomputed from u (4 fma) instead of materialized (saves ~67MB/layer).

constexpr int   Bsz = 32;
constexpr int   Lsz = 4096;
constexpr int   NC  = 32;          // chunks per sequence
constexpr int   CL  = 128;         // chunk length (L/NC)
constexpr float SRinv = 1.0f / 4096.0f;

__device__ __forceinline__ float sigmoidf_(float v) {
    return 1.0f / (1.0f + __expf(-v));
}

// ---------------- K1: preprocess + per-chunk (P,S) ----------------
__global__ __launch_bounds__(128) void k_chunk_scan(
    const float* __restrict__ xin,    // [B,L] layer input
    const float* __restrict__ W_in,   // [4]  (u0,u1,z0,z1 weights)
    const float* __restrict__ conv_w, // [2,4]
    const float* __restrict__ conv_b, // [2]
    const float* __restrict__ W_x,    // [2,129]
    const float* __restrict__ W_dt,   // [2]
    const float* __restrict__ b_dt,   // [2]
    const float* __restrict__ A_log,  // [2,64]
    float4* __restrict__ ud,          // [B*L] {u0,u1,d0,d1}
    float*  __restrict__ Pc,          // [B,NC,128]
    float*  __restrict__ Sc)          // [B,NC,128]
{
    const int c = blockIdx.x, b = blockIdx.y, tid = threadIdx.x;
    __shared__ float  xs[CL + 3];
    __shared__ float4 s_ud[CL];
    const int base = b * Lsz + c * CL;

    // load x with left halo of 3 (zero-padded)
    for (int i = tid; i < CL + 3; i += 128) {
        int l = c * CL + i - 3;
        xs[i] = (l >= 0) ? xin[b * Lsz + l] : 0.0f;
    }
    __syncthreads();

    // preprocess: thread t handles position l = t
    {
        const int t = tid;
        float x0 = xs[t], x1 = xs[t + 1], x2 = xs[t + 2], x3 = xs[t + 3];
        float u[2];
        #pragma unroll
        for (int e = 0; e < 2; e++) {
            float v = W_in[e] * (x0 * conv_w[e * 4 + 0] + x1 * conv_w[e * 4 + 1] +
                                 x2 * conv_w[e * 4 + 2] + x3 * conv_w[e * 4 + 3]) +
                      conv_b[e];
            u[e] = v * sigmoidf_(v);   // silu
        }
        float dt = u[0] * W_x[0] + u[1] * W_x[129];
        float dl[2];
        #pragma unroll
        for (int e = 0; e < 2; e++) {
            float a = dt * W_dt[e] + b_dt[e];
            float sp = (a > 20.0f) ? a : log1pf(__expf(a));
            dl[e] = sp * SRinv;
        }
        float4 v4 = make_float4(u[0], u[1], dl[0], dl[1]);
        s_ud[t] = v4;
        ud[base + t] = v4;
    }
    __syncthreads();

    // chunk scan: thread = (e,n)
    const int e = tid >> 6, n = tid & 63;
    const float Aen = -__expf(A_log[e * 64 + n]);
    const float wb0 = W_x[1 + n], wb1 = W_x[129 + 1 + n];
    float P = 1.0f, S = 0.0f;
    #pragma unroll 8
    for (int l = 0; l < CL; l++) {
        float4 v = s_ud[l];
        float ue = e ? v.y : v.x;
        float d  = e ? v.w : v.z;
        float Bn = v.x * wb0 + v.y * wb1;
        float dA = __expf(d * Aen);
        S = dA * S + (d * ue) * Bn;
        P *= dA;
    }
    const int idx = (b * NC + c) * 128 + tid;
    Pc[idx] = P;
    Sc[idx] = S;
}

// ---------------- K2: serial combine over chunks ----------------
__global__ __launch_bounds__(256) void k_combine(
    const float* __restrict__ Pc, const float* __restrict__ Sc,
    float* __restrict__ Hinit)    // [B,NC,128] state entering each chunk
{
    const int idx = blockIdx.x * 256 + threadIdx.x;   // b*128 + en  (4096 total)
    const int b = idx >> 7, en = idx & 127;
    float h = 0.0f;
    #pragma unroll
    for (int c = 0; c < NC; c++) {
        int o = (b * NC + c) * 128 + en;
        Hinit[o] = h;
        h = Pc[o] * h + Sc[o];
    }
}

// ---------------- K3: re-scan with init state + reduction + epilogue ----------------
__global__ __launch_bounds__(128) void k_output(
    const float* __restrict__ xin,
    const float4* __restrict__ ud,
    const float* __restrict__ Hinit,
    const float* __restrict__ W_in,   // z weights at [2],[3]
    const float* __restrict__ W_x,
    const float* __restrict__ A_log,
    const float* __restrict__ D_skip, // [2]
    const float* __restrict__ W_out,  // [2]
    float* __restrict__ out)          // [B,L]
{
    const int c = blockIdx.x, b = blockIdx.y, tid = threadIdx.x;
    constexpr int T = 64;             // steps per reduction tile
    __shared__ float4 s_ud[CL];
    __shared__ float  xs[CL];
    __shared__ float  ps[128 * 65];   // row (t*2+e), stride 65 (bank-safe)
    __shared__ float  ys[T * 2];
    const int base = b * Lsz + c * CL;

    s_ud[tid] = ud[base + tid];
    xs[tid]   = xin[base + tid];

    const int e = tid >> 6, n = tid & 63;
    const float Aen = -__expf(A_log[e * 64 + n]);
    const float wb0 = W_x[1 + n],  wb1 = W_x[129 + 1 + n];
    const float wc0 = W_x[65 + n], wc1 = W_x[129 + 65 + n];
    float h = Hinit[(b * NC + c) * 128 + tid];
    const float wz0 = W_in[2], wz1 = W_in[3];
    const float D0 = D_skip[0], D1 = D_skip[1];
    const float wo0 = W_out[0], wo1 = W_out[1];
    __syncthreads();

    for (int tile = 0; tile < CL / T; tile++) {
        #pragma unroll 8
        for (int t = 0; t < T; t++) {
            float4 v = s_ud[tile * T + t];
            float ue = e ? v.y : v.x;
            float d  = e ? v.w : v.z;
            float Bn = v.x * wb0 + v.y * wb1;
            float Cn = v.x * wc0 + v.y * wc1;
            float dA = __expf(d * Aen);
            h = dA * h + (d * ue) * Bn;
            ps[(t * 2 + e) * 65 + n] = h * Cn;
        }
        __syncthreads();
        // reduce row r=tid over n (64 values), add u*D
        {
            const int r = tid, t = r >> 1, re = r & 1;
            const float* row = &ps[r * 65];
            float a0 = 0, a1 = 0, a2 = 0, a3 = 0;
            #pragma unroll
            for (int j = 0; j < 64; j += 4) {
                a0 += row[j]; a1 += row[j + 1]; a2 += row[j + 2]; a3 += row[j + 3];
            }
            float4 v = s_ud[tile * T + t];
            float ue = re ? v.y : v.x;
            ys[r] = (a0 + a1) + (a2 + a3) + ue * (re ? D1 : D0);
        }
        __syncthreads();
        if (tid < T) {
            int l = tile * T + tid;
            float y0 = ys[tid * 2], y1 = ys[tid * 2 + 1];
            float xv = xs[l];
            float z0 = xv * wz0, z1 = xv * wz1;
            out[base + l] = y0 * (z0 * sigmoidf_(z0)) * wo0 +
                            y1 * (z1 * sigmoidf_(z1)) * wo1 + xv;
        }
        __syncthreads();
    }
}

extern "C" void kernel_launch(void* const* d_in, const int* in_sizes, int n_in,
                              void* d_out, int out_size, void* d_ws, size_t ws_size,
                              hipStream_t stream) {
    const float* x      = (const float*)d_in[0];
    const float* W_in   = (const float*)d_in[1];   // [4,1,4]
    const float* conv_w = (const float*)d_in[2];   // [4,2,4]
    const float* conv_b = (const float*)d_in[3];   // [4,2]
    const float* W_x    = (const float*)d_in[4];   // [4,2,129]
    const float* W_dt   = (const float*)d_in[5];   // [4,1,2]
    const float* b_dt   = (const float*)d_in[6];   // [4,2]
    const float* A_log  = (const float*)d_in[7];   // [4,2,64]
    const float* D_skip = (const float*)d_in[8];   // [4,2]
    const float* W_out  = (const float*)d_in[9];   // [4,2,1]
    float* out = (float*)d_out;

    float* ws   = (float*)d_ws;
    float4* ud  = (float4*)ws;                       // B*L float4s = B*L*4 floats
    float* Pc   = ws + (size_t)Bsz * Lsz * 4;
    float* Sc   = Pc + (size_t)Bsz * NC * 128;
    float* Hi   = Sc + (size_t)Bsz * NC * 128;
    float* buf0 = Hi + (size_t)Bsz * NC * 128;
    float* buf1 = buf0 + (size_t)Bsz * Lsz;

    const float* cur = x;
    for (int i = 0; i < 4; i++) {
        float* o = (i == 3) ? out : ((i & 1) ? buf1 : buf0);
        k_chunk_scan<<<dim3(NC, Bsz), 128, 0, stream>>>(
            cur, W_in + i * 4, conv_w + i * 8, conv_b + i * 2,
            W_x + i * 258, W_dt + i * 2, b_dt + i * 2, A_log + i * 128,
            ud, Pc, Sc);
        k_combine<<<16, 256, 0, stream>>>(Pc, Sc, Hi);
        k_output<<<dim3(NC, Bsz), 128, 0, stream>>>(
            cur, ud, Hi, W_in + i * 4, W_x + i * 258,
            A_log + i * 128, D_skip + i * 2, W_out + i * 2, o);
        cur = o;
    }
}